// Round 1
// baseline (694.698 us; speedup 1.0000x reference)
//
#include <hip/hip_runtime.h>

#define WAY 5
#define NQ 75
#define CCH 64
#define P 400              // 20*20 positions
#define PS (P*CCH)         // 25600 elements per sample
#define NPAIR (NQ*WAY)     // 375
#define TEMP_INV 0.2f      // 1/5.0

typedef unsigned short u16;
typedef __attribute__((ext_vector_type(8))) short s16x8;
typedef __attribute__((ext_vector_type(4))) float f32x4;

__device__ __forceinline__ u16 f2bf(float f) {
  unsigned u = __float_as_uint(f);
  u += 0x7fffu + ((u >> 16) & 1u);
  return (u16)(u >> 16);
}
__device__ __forceinline__ float bf2f(u16 h) {
  return __uint_as_float(((unsigned)h) << 16);
}
__device__ __forceinline__ float wave_sum(float v) {
  v += __shfl_xor(v, 1);  v += __shfl_xor(v, 2);  v += __shfl_xor(v, 4);
  v += __shfl_xor(v, 8);  v += __shfl_xor(v, 16); v += __shfl_xor(v, 32);
  return v;
}

// ---------------- prep: normalize_feature -> conv1x1 -> BN -> ReLU -> L2norm ----------------
// one wave per spatial position; lane = channel
__global__ __launch_bounds__(256) void prep_kernel(
    const float* __restrict__ spt, const float* __restrict__ qry,
    const float* __restrict__ conv_w,
    const float* __restrict__ bng, const float* __restrict__ bnb,
    const float* __restrict__ bnm, const float* __restrict__ bnv,
    u16* __restrict__ sAh, u16* __restrict__ sAl,
    u16* __restrict__ qAh, u16* __restrict__ qAl,
    float* __restrict__ snT, float* __restrict__ qnT)
{
  __shared__ float wlds[64 * 65];   // padded: bank (o+c)%32 -> 2-way (free)
  const int tid = threadIdx.x;
  for (int t = tid; t < 4096; t += 256) wlds[(t >> 6) * 65 + (t & 63)] = conv_w[t];
  __syncthreads();
  const int lane = tid & 63, wv = tid >> 6;
  const float bs = bng[lane] * rsqrtf(bnv[lane] + 1e-5f);
  const float bm = bnm[lane], bb = bnb[lane];
  const int gw = blockIdx.x * 4 + wv;            // 0..1999
  for (int i = 0; i < 16; ++i) {
    const int pg = gw + 2000 * i;                // 0..31999
    const int n = pg / 400, p = pg - n * 400;
    const float* src; u16* dAh; u16* dAl; float* dN;
    if (n < WAY) { src = spt + n * PS;        dAh = sAh + n * PS;        dAl = sAl + n * PS;        dN = snT + n * PS; }
    else         { int m = n - WAY; src = qry + m * PS; dAh = qAh + m * PS; dAl = qAl + m * PS; dN = qnT + m * PS; }
    const float x = src[lane * 400 + p];
    const float mu = wave_sum(x) * (1.0f / 64.0f);
    const float xm = x - mu;
    dN[p * 64 + lane] = xm;                      // [pos][c] f32 for pooling
    float y = 0.f;
#pragma unroll
    for (int c = 0; c < 64; ++c)
      y = fmaf(wlds[lane * 65 + c], __shfl(xm, c), y);
    y = fmaf(y - bm, bs, bb);
    y = fmaxf(y, 0.f);
    const float n2 = wave_sum(y * y);
    const float rn = 1.0f / fmaxf(sqrtf(n2), 1e-8f);
    const float o = y * rn;
    const u16 h = f2bf(o);
    const u16 l = f2bf(o - bf2f(h));             // split-bf16 residual
    dAh[p * 64 + lane] = h;
    dAl[p * 64 + lane] = l;
  }
}

// ---------------- corr: X = F1 . F2^T (over C), per-b-column gaussnorm+softmax over a,
//                  attn_out[a] = sum_b weight[a,b] ----------------
// block = one (q,w) pair; wave owns 16-column tiles (bt = wv, wv+4, ...)
__global__ __launch_bounds__(256, 1) void corr_kernel(
    const u16* __restrict__ sAh, const u16* __restrict__ sAl,
    const u16* __restrict__ qAh, const u16* __restrict__ qAl,
    float* __restrict__ attn_out, const int mode)
{
  const int pair = blockIdx.x;
  const int q = pair / WAY, w = pair - q * WAY;
  const u16 *F1h, *F1l, *F2h, *F2l;
  if (mode == 0) { F1h = sAh + w * PS; F1l = sAl + w * PS; F2h = qAh + q * PS; F2l = qAl + q * PS; }
  else           { F1h = qAh + q * PS; F1l = qAl + q * PS; F2h = sAh + w * PS; F2l = sAl + w * PS; }
  float* out = attn_out + pair * P;

  const int tid = threadIdx.x, lane = tid & 63, wv = tid >> 6;
  const int l15 = lane & 15, g = lane >> 4;

  __shared__ float attn_lds[4][400];

  f32x4 aacc[25];
#pragma unroll
  for (int t = 0; t < 25; ++t) aacc[t] = (f32x4){0.f, 0.f, 0.f, 0.f};

  for (int bt = wv; bt < 25; bt += 4) {
    const int boff = (bt * 16 + l15) * 64 + g * 8;
    const s16x8 bh0 = *(const s16x8*)(F2h + boff);
    const s16x8 bh1 = *(const s16x8*)(F2h + boff + 32);
    const s16x8 bl0 = *(const s16x8*)(F2l + boff);
    const s16x8 bl1 = *(const s16x8*)(F2l + boff + 32);
    f32x4 acc[25];
#pragma unroll
    for (int at = 0; at < 25; ++at) {
      const int aoff = (at * 16 + l15) * 64 + g * 8;
      const s16x8 ah0 = *(const s16x8*)(F1h + aoff);
      const s16x8 ah1 = *(const s16x8*)(F1h + aoff + 32);
      const s16x8 al0 = *(const s16x8*)(F1l + aoff);
      const s16x8 al1 = *(const s16x8*)(F1l + aoff + 32);
      f32x4 c = {0.f, 0.f, 0.f, 0.f};
      c = __builtin_amdgcn_mfma_f32_16x16x32_bf16(ah0, bh0, c, 0, 0, 0);
      c = __builtin_amdgcn_mfma_f32_16x16x32_bf16(ah1, bh1, c, 0, 0, 0);
      c = __builtin_amdgcn_mfma_f32_16x16x32_bf16(al0, bh0, c, 0, 0, 0);
      c = __builtin_amdgcn_mfma_f32_16x16x32_bf16(al1, bh1, c, 0, 0, 0);
      c = __builtin_amdgcn_mfma_f32_16x16x32_bf16(ah0, bl0, c, 0, 0, 0);
      c = __builtin_amdgcn_mfma_f32_16x16x32_bf16(ah1, bl1, c, 0, 0, 0);
      acc[at] = c;
    }
    // per-column stats over the 400 a-values (100 local + lanes ^16,^32)
    float sum = 0.f, ssq = 0.f, mx = -3.0e38f;
#pragma unroll
    for (int at = 0; at < 25; ++at)
#pragma unroll
      for (int r = 0; r < 4; ++r) {
        const float v = acc[at][r];
        sum += v; ssq = fmaf(v, v, ssq); mx = fmaxf(mx, v);
      }
    sum += __shfl_xor(sum, 16); sum += __shfl_xor(sum, 32);
    ssq += __shfl_xor(ssq, 16); ssq += __shfl_xor(ssq, 32);
    mx = fmaxf(mx, __shfl_xor(mx, 16)); mx = fmaxf(mx, __shfl_xor(mx, 32));
    const float mean = sum * (1.0f / 400.0f);
    float var = (ssq - 400.0f * mean * mean) * (1.0f / 399.0f);  // ddof=1
    var = fmaxf(var, 0.f);
    const float alpha = rsqrtf(var + 1e-5f) * TEMP_INV;          // rstd / TEMP
    float se = 0.f;
#pragma unroll
    for (int at = 0; at < 25; ++at)
#pragma unroll
      for (int r = 0; r < 4; ++r) {
        const float e = __expf((acc[at][r] - mx) * alpha);       // exp((z-zmax)/T)
        acc[at][r] = e; se += e;
      }
    se += __shfl_xor(se, 16); se += __shfl_xor(se, 32);
    const float inv = 1.0f / se;
#pragma unroll
    for (int at = 0; at < 25; ++at)
#pragma unroll
      for (int r = 0; r < 4; ++r)
        aacc[at][r] = fmaf(acc[at][r], inv, aacc[at][r]);
  }
  // sum over this wave's columns (lanes ^1,^2,^4,^8), park in LDS, merge 4 waves
#pragma unroll
  for (int at = 0; at < 25; ++at)
#pragma unroll
    for (int r = 0; r < 4; ++r) {
      float v = aacc[at][r];
      v += __shfl_xor(v, 1); v += __shfl_xor(v, 2);
      v += __shfl_xor(v, 4); v += __shfl_xor(v, 8);
      if (l15 == 0) attn_lds[wv][at * 16 + g * 4 + r] = v;
    }
  __syncthreads();
  for (int a = tid; a < P; a += 256)
    out[a] = attn_lds[0][a] + attn_lds[1][a] + attn_lds[2][a] + attn_lds[3][a];
}

// ---------------- pool: attention-weighted mean pooling + cosine ----------------
__global__ __launch_bounds__(256) void pool_kernel(
    const float* __restrict__ snT, const float* __restrict__ qnT,
    const float* __restrict__ attn_s, const float* __restrict__ attn_q,
    const float* __restrict__ scale, float* __restrict__ out)
{
  const int pair = blockIdx.x;
  const int q = pair / WAY, w = pair - q * WAY;
  const int tid = threadIdx.x, lane = tid & 63, wv = tid >> 6;
  const float* sn = snT + w * PS;
  const float* qn = qnT + q * PS;
  const float* as_ = attn_s + pair * P;
  const float* aq_ = attn_q + pair * P;
  float accs = 0.f, accq = 0.f;
  for (int p = wv; p < P; p += 4) {
    accs = fmaf(as_[p], sn[p * 64 + lane], accs);
    accq = fmaf(aq_[p], qn[p * 64 + lane], accq);
  }
  __shared__ float buf[2][4][64];
  buf[0][wv][lane] = accs;
  buf[1][wv][lane] = accq;
  __syncthreads();
  if (wv == 0) {
    const float sa = (buf[0][0][lane] + buf[0][1][lane] + buf[0][2][lane] + buf[0][3][lane]) * (1.0f / 400.0f);
    const float qa = (buf[1][0][lane] + buf[1][1][lane] + buf[1][2][lane] + buf[1][3][lane]) * (1.0f / 400.0f);
    const float d   = wave_sum(sa * qa);
    const float ns  = wave_sum(sa * sa);
    const float nq2 = wave_sum(qa * qa);
    if (lane == 0) {
      const float den = fmaxf(sqrtf(ns), 1e-6f) * fmaxf(sqrtf(nq2), 1e-6f);
      out[pair] = d / den * scale[0];
    }
  }
}

extern "C" void kernel_launch(void* const* d_in, const int* in_sizes, int n_in,
                              void* d_out, int out_size, void* d_ws, size_t ws_size,
                              hipStream_t stream) {
  const float* spt    = (const float*)d_in[0];
  const float* qry    = (const float*)d_in[1];
  const float* conv_w = (const float*)d_in[2];
  const float* bng    = (const float*)d_in[3];
  const float* bnb    = (const float*)d_in[4];
  const float* bnm    = (const float*)d_in[5];
  const float* bnv    = (const float*)d_in[6];
  const float* scale  = (const float*)d_in[7];
  float* out = (float*)d_out;

  char* p = (char*)d_ws;
  u16* sAh = (u16*)p;    p += (size_t)WAY * PS * 2;
  u16* sAl = (u16*)p;    p += (size_t)WAY * PS * 2;
  u16* qAh = (u16*)p;    p += (size_t)NQ * PS * 2;
  u16* qAl = (u16*)p;    p += (size_t)NQ * PS * 2;
  float* snT = (float*)p;    p += (size_t)WAY * PS * 4;
  float* qnT = (float*)p;    p += (size_t)NQ * PS * 4;
  float* attn_s = (float*)p; p += (size_t)NPAIR * P * 4;
  float* attn_q = (float*)p;

  prep_kernel<<<dim3(500), dim3(256), 0, stream>>>(
      spt, qry, conv_w, bng, bnb, bnm, bnv, sAh, sAl, qAh, qAl, snT, qnT);
  corr_kernel<<<dim3(NPAIR), dim3(256), 0, stream>>>(
      sAh, sAl, qAh, qAl, attn_s, 0);
  corr_kernel<<<dim3(NPAIR), dim3(256), 0, stream>>>(
      sAh, sAl, qAh, qAl, attn_q, 1);
  pool_kernel<<<dim3(NPAIR), dim3(256), 0, stream>>>(
      snT, qnT, attn_s, attn_q, scale, out);
}

// Round 2
// 177.626 us; speedup vs baseline: 3.9110x; 3.9110x over previous
//
#include <hip/hip_runtime.h>

#define WAY 5
#define NQ 75
#define P 400              // 20*20 positions
#define PS (P*64)          // 25600 elements per sample
#define NPAIR (NQ*WAY)     // 375
#define TEMP_INV 0.2f      // 1/5.0

typedef unsigned short u16;
typedef __attribute__((ext_vector_type(8))) short s16x8;
typedef __attribute__((ext_vector_type(4))) float f32x4;

__device__ __forceinline__ u16 f2bf(float f) {
  unsigned u = __float_as_uint(f);
  u += 0x7fffu + ((u >> 16) & 1u);
  return (u16)(u >> 16);
}
__device__ __forceinline__ float bf2f(u16 h) {
  return __uint_as_float(((unsigned)h) << 16);
}
__device__ __forceinline__ float wave_sum(float v) {
  v += __shfl_xor(v, 1);  v += __shfl_xor(v, 2);  v += __shfl_xor(v, 4);
  v += __shfl_xor(v, 8);  v += __shfl_xor(v, 16); v += __shfl_xor(v, 32);
  return v;
}

// ---------------- prep: normalize_feature -> conv1x1 -> BN -> ReLU -> L2norm ----------------
// 800 blocks = 80 samples x 10 chunks of 40 positions. LDS-transposed staging for
// coalesced global reads; wave-per-position compute (lane = channel).
__global__ __launch_bounds__(256) void prep_kernel(
    const float* __restrict__ spt, const float* __restrict__ qry,
    const float* __restrict__ conv_w,
    const float* __restrict__ bng, const float* __restrict__ bnb,
    const float* __restrict__ bnm, const float* __restrict__ bnv,
    u16* __restrict__ sAh, u16* __restrict__ sAl,
    u16* __restrict__ qAh, u16* __restrict__ qAl,
    float* __restrict__ snT, float* __restrict__ qnT)
{
  __shared__ float xt[40 * 65];
  __shared__ float wl[64 * 65];
  const int tid = threadIdx.x;
  const int n = blockIdx.x / 10, p0 = (blockIdx.x - n * 10) * 40;
  const float* src = (n < WAY) ? (spt + n * PS) : (qry + (n - WAY) * PS);
  for (int i = tid; i < 4096; i += 256) wl[(i >> 6) * 65 + (i & 63)] = conv_w[i];
  for (int i = tid; i < 2560; i += 256) {
    const int c = i / 40, pp = i - c * 40;
    xt[pp * 65 + c] = src[c * 400 + p0 + pp];          // coalesced 40-float runs
  }
  __syncthreads();
  const int lane = tid & 63, wv = tid >> 6;
  const float bs = bng[lane] * rsqrtf(bnv[lane] + 1e-5f);
  const float bm = bnm[lane], bb = bnb[lane];
  u16* dAh; u16* dAl; float* dN;
  if (n < WAY) { dAh = sAh + n * PS; dAl = sAl + n * PS; dN = snT + n * PS; }
  else { const int m = n - WAY; dAh = qAh + m * PS; dAl = qAl + m * PS; dN = qnT + m * PS; }
  for (int i = 0; i < 10; ++i) {
    const int p = wv * 10 + i;
    const float x = xt[p * 65 + lane];
    const float mu = wave_sum(x) * (1.0f / 64.0f);
    const float xm = x - mu;
    dN[(p0 + p) * 64 + lane] = xm;                     // [pos][c] f32 for pooling
    float y = 0.f;
#pragma unroll
    for (int c = 0; c < 64; ++c)
      y = fmaf(wl[lane * 65 + c], __shfl(xm, c), y);
    y = fmaf(y - bm, bs, bb);
    y = fmaxf(y, 0.f);
    const float n2 = wave_sum(y * y);
    const float rn = 1.0f / fmaxf(sqrtf(n2), 1e-8f);
    const float o = y * rn;
    const u16 h = f2bf(o);
    const u16 l = f2bf(o - bf2f(h));                   // split-bf16 residual
    dAh[(p0 + p) * 64 + lane] = h;
    dAl[(p0 + p) * 64 + lane] = l;
  }
}

// ---------------- corr: X[a,b] = F1[a].F2[b]; per-b gaussnorm+softmax over a (400);
//                  attn[a] = sum_b w[a,b]. Both modes in one launch. ----------------
// Block = (mode,pair), 8 waves. F1(hi+lo) staged in 102.4KB LDS (XOR-swizzled).
// Swapped MFMA: mfma(A=F2set, B=F1tile) -> lane l15 = a-index, (g,r) = b-column.
// Per wave: b-tile sets {wv, wv+8, wv+16} (+24 for wv==0), one LDS sweep per set.
__global__ __launch_bounds__(512, 1) void corr_kernel(
    const u16* __restrict__ sAh, const u16* __restrict__ sAl,
    const u16* __restrict__ qAh, const u16* __restrict__ qAl,
    float* __restrict__ attn_s, float* __restrict__ attn_q)
{
  __shared__ u16 f1h[25600];        // 51.2 KB
  __shared__ u16 f1l[25600];        // 51.2 KB
  __shared__ float attn_sm[8 * 400];  // 12.8 KB
  const int bid = blockIdx.x;
  const int mode = (bid >= NPAIR) ? 1 : 0;
  const int pair = mode ? (bid - NPAIR) : bid;
  const int q = pair / WAY, w = pair - q * WAY;
  const u16 *F1h, *F1l, *F2h, *F2l; float* out;
  if (!mode) { F1h = sAh + w * PS; F1l = sAl + w * PS; F2h = qAh + q * PS; F2l = qAl + q * PS; out = attn_s + pair * P; }
  else       { F1h = qAh + q * PS; F1l = qAl + q * PS; F2h = sAh + w * PS; F2l = sAl + w * PS; out = attn_q + pair * P; }

  const int tid = threadIdx.x, lane = tid & 63, wv = tid >> 6;
  const int l15 = lane & 15, g = (lane >> 4) & 3;

  // stage F1 hi+lo into LDS, XOR-swizzled (row = 128B; swz byte ^= (row&7)<<4)
  for (int i = tid; i < 3200; i += 512) {
    const unsigned sw = ((unsigned)(i * 16)) ^ ((((unsigned)i >> 3) & 7u) << 4);
    *(s16x8*)((char*)f1h + sw) = *(const s16x8*)(F1h + i * 8);
    *(s16x8*)((char*)f1l + sw) = *(const s16x8*)(F1l + i * 8);
  }
  for (int i = lane; i < P; i += 64) attn_sm[wv * P + i] = 0.f;
  __syncthreads();

  const unsigned sx = ((unsigned)(l15 & 7)) << 4;
  const unsigned base0 = (unsigned)(l15 * 128 + g * 16);
  const unsigned b0 = base0 ^ sx;
  const unsigned b1 = (base0 + 64u) ^ sx;
  const char* f1hB = (const char*)f1h;
  const char* f1lB = (const char*)f1l;

  for (int s = 0; s < 4; ++s) {
    const int tile = wv + 8 * s;
    if (tile >= 25) continue;                       // wave-uniform
    // A-operand: the set's 16 b-columns (from global, once)
    const int aoffB = (tile * 16 + l15) * 64 + g * 8;
    const s16x8 Ah0 = *(const s16x8*)(F2h + aoffB);
    const s16x8 Ah1 = *(const s16x8*)(F2h + aoffB + 32);
    const s16x8 Al0 = *(const s16x8*)(F2l + aoffB);
    const s16x8 Al1 = *(const s16x8*)(F2l + aoffB + 32);

    f32x4 acc[25];
#pragma unroll
    for (int at = 0; at < 25; ++at) {
      const s16x8 Bh0 = *(const s16x8*)(f1hB + at * 2048 + b0);
      const s16x8 Bh1 = *(const s16x8*)(f1hB + at * 2048 + b1);
      const s16x8 Bl0 = *(const s16x8*)(f1lB + at * 2048 + b0);
      const s16x8 Bl1 = *(const s16x8*)(f1lB + at * 2048 + b1);
      f32x4 c = {0.f, 0.f, 0.f, 0.f};
      c = __builtin_amdgcn_mfma_f32_16x16x32_bf16(Ah0, Bh0, c, 0, 0, 0);
      c = __builtin_amdgcn_mfma_f32_16x16x32_bf16(Ah1, Bh1, c, 0, 0, 0);
      c = __builtin_amdgcn_mfma_f32_16x16x32_bf16(Al0, Bh0, c, 0, 0, 0);
      c = __builtin_amdgcn_mfma_f32_16x16x32_bf16(Al1, Bh1, c, 0, 0, 0);
      c = __builtin_amdgcn_mfma_f32_16x16x32_bf16(Ah0, Bl0, c, 0, 0, 0);
      c = __builtin_amdgcn_mfma_f32_16x16x32_bf16(Ah1, Bl1, c, 0, 0, 0);
      acc[at] = c;
    }
    // per-column (b) stats over 400 a-values: per-lane over at, then shfl over l15
    float sum0 = 0.f, sum1 = 0.f, sum2 = 0.f, sum3 = 0.f;
    float ssq0 = 0.f, ssq1 = 0.f, ssq2 = 0.f, ssq3 = 0.f;
#pragma unroll
    for (int at = 0; at < 25; ++at) {
      sum0 += acc[at][0]; ssq0 = fmaf(acc[at][0], acc[at][0], ssq0);
      sum1 += acc[at][1]; ssq1 = fmaf(acc[at][1], acc[at][1], ssq1);
      sum2 += acc[at][2]; ssq2 = fmaf(acc[at][2], acc[at][2], ssq2);
      sum3 += acc[at][3]; ssq3 = fmaf(acc[at][3], acc[at][3], ssq3);
    }
    float mean[4], alpha[4];
    float sums[4] = {sum0, sum1, sum2, sum3};
    float ssqs[4] = {ssq0, ssq1, ssq2, ssq3};
#pragma unroll
    for (int r = 0; r < 4; ++r) {
      float s_ = sums[r], q_ = ssqs[r];
      s_ += __shfl_xor(s_, 1); s_ += __shfl_xor(s_, 2); s_ += __shfl_xor(s_, 4); s_ += __shfl_xor(s_, 8);
      q_ += __shfl_xor(q_, 1); q_ += __shfl_xor(q_, 2); q_ += __shfl_xor(q_, 4); q_ += __shfl_xor(q_, 8);
      const float m_ = s_ * (1.0f / 400.0f);
      float var = fmaf(-400.0f * m_, m_, q_) * (1.0f / 399.0f);  // ddof=1
      var = fmaxf(var, 0.f);
      alpha[r] = rsqrtf(var + 1e-5f) * TEMP_INV;   // rstd/TEMP
      mean[r] = m_;
    }
    // exp (no max-shift needed: |z|/T <= sqrt(399)/5 ~= 4) + column sums
    float se0 = 0.f, se1 = 0.f, se2 = 0.f, se3 = 0.f;
#pragma unroll
    for (int at = 0; at < 25; ++at) {
      const float e0 = __expf((acc[at][0] - mean[0]) * alpha[0]);
      const float e1 = __expf((acc[at][1] - mean[1]) * alpha[1]);
      const float e2 = __expf((acc[at][2] - mean[2]) * alpha[2]);
      const float e3 = __expf((acc[at][3] - mean[3]) * alpha[3]);
      acc[at][0] = e0; acc[at][1] = e1; acc[at][2] = e2; acc[at][3] = e3;
      se0 += e0; se1 += e1; se2 += e2; se3 += e3;
    }
    float inv[4];
    float ses[4] = {se0, se1, se2, se3};
#pragma unroll
    for (int r = 0; r < 4; ++r) {
      float s_ = ses[r];
      s_ += __shfl_xor(s_, 1); s_ += __shfl_xor(s_, 2); s_ += __shfl_xor(s_, 4); s_ += __shfl_xor(s_, 8);
      inv[r] = 1.0f / s_;
    }
    // attn[a] += sum over this set's 16 b-columns of e*inv
#pragma unroll
    for (int at = 0; at < 25; ++at) {
      float t = acc[at][0] * inv[0];
      t = fmaf(acc[at][1], inv[1], t);
      t = fmaf(acc[at][2], inv[2], t);
      t = fmaf(acc[at][3], inv[3], t);
      t += __shfl_xor(t, 16); t += __shfl_xor(t, 32);
      if (lane < 16) attn_sm[wv * P + at * 16 + lane] += t;
    }
  }
  __syncthreads();
  for (int a = tid; a < P; a += 512) {
    float s_ = 0.f;
#pragma unroll
    for (int k = 0; k < 8; ++k) s_ += attn_sm[k * P + a];
    out[a] = s_;
  }
}

// ---------------- pool: attention-weighted mean pooling + cosine ----------------
__global__ __launch_bounds__(256) void pool_kernel(
    const float* __restrict__ snT, const float* __restrict__ qnT,
    const float* __restrict__ attn_s, const float* __restrict__ attn_q,
    const float* __restrict__ scale, float* __restrict__ out)
{
  const int pair = blockIdx.x;
  const int q = pair / WAY, w = pair - q * WAY;
  const int tid = threadIdx.x, lane = tid & 63, wv = tid >> 6;
  const float* sn = snT + w * PS;
  const float* qn = qnT + q * PS;
  const float* as_ = attn_s + pair * P;
  const float* aq_ = attn_q + pair * P;
  float accs = 0.f, accq = 0.f;
  for (int p = wv; p < P; p += 4) {
    accs = fmaf(as_[p], sn[p * 64 + lane], accs);
    accq = fmaf(aq_[p], qn[p * 64 + lane], accq);
  }
  __shared__ float buf[2][4][64];
  buf[0][wv][lane] = accs;
  buf[1][wv][lane] = accq;
  __syncthreads();
  if (wv == 0) {
    const float sa = (buf[0][0][lane] + buf[0][1][lane] + buf[0][2][lane] + buf[0][3][lane]) * (1.0f / 400.0f);
    const float qa = (buf[1][0][lane] + buf[1][1][lane] + buf[1][2][lane] + buf[1][3][lane]) * (1.0f / 400.0f);
    const float d   = wave_sum(sa * qa);
    const float ns  = wave_sum(sa * sa);
    const float nq2 = wave_sum(qa * qa);
    if (lane == 0) {
      const float den = fmaxf(sqrtf(ns), 1e-6f) * fmaxf(sqrtf(nq2), 1e-6f);
      out[pair] = d / den * scale[0];
    }
  }
}

extern "C" void kernel_launch(void* const* d_in, const int* in_sizes, int n_in,
                              void* d_out, int out_size, void* d_ws, size_t ws_size,
                              hipStream_t stream) {
  const float* spt    = (const float*)d_in[0];
  const float* qry    = (const float*)d_in[1];
  const float* conv_w = (const float*)d_in[2];
  const float* bng    = (const float*)d_in[3];
  const float* bnb    = (const float*)d_in[4];
  const float* bnm    = (const float*)d_in[5];
  const float* bnv    = (const float*)d_in[6];
  const float* scale  = (const float*)d_in[7];
  float* out = (float*)d_out;

  char* p = (char*)d_ws;
  u16* sAh = (u16*)p;    p += (size_t)WAY * PS * 2;
  u16* sAl = (u16*)p;    p += (size_t)WAY * PS * 2;
  u16* qAh = (u16*)p;    p += (size_t)NQ * PS * 2;
  u16* qAl = (u16*)p;    p += (size_t)NQ * PS * 2;
  float* snT = (float*)p;    p += (size_t)WAY * PS * 4;
  float* qnT = (float*)p;    p += (size_t)NQ * PS * 4;
  float* attn_s = (float*)p; p += (size_t)NPAIR * P * 4;
  float* attn_q = (float*)p;

  prep_kernel<<<dim3(800), dim3(256), 0, stream>>>(
      spt, qry, conv_w, bng, bnb, bnm, bnv, sAh, sAl, qAh, qAl, snT, qnT);
  corr_kernel<<<dim3(2 * NPAIR), dim3(512), 0, stream>>>(
      sAh, sAl, qAh, qAl, attn_s, attn_q);
  pool_kernel<<<dim3(NPAIR), dim3(256), 0, stream>>>(
      snT, qnT, attn_s, attn_q, scale, out);
}

// Round 3
// 150.149 us; speedup vs baseline: 4.6267x; 1.1830x over previous
//
#include <hip/hip_runtime.h>

#define WAY 5
#define NQ 75
#define P 400              // 20*20 positions
#define PS (P*64)          // 25600 elements per sample
#define NPAIR (NQ*WAY)     // 375
#define TEMP_INV 0.2f      // 1/5.0

typedef unsigned short u16;
typedef _Float16 f16;
typedef __attribute__((ext_vector_type(8))) _Float16 f16x8;
typedef __attribute__((ext_vector_type(4))) float f32x4;

__device__ __forceinline__ float wave_sum(float v) {
  v += __shfl_xor(v, 1);  v += __shfl_xor(v, 2);  v += __shfl_xor(v, 4);
  v += __shfl_xor(v, 8);  v += __shfl_xor(v, 16); v += __shfl_xor(v, 32);
  return v;
}

// ---------------- prep: normalize_feature -> conv1x1 -> BN -> ReLU -> L2norm ----------------
// 800 blocks = 80 samples x 10 chunks of 40 positions. LDS-transposed staging for
// coalesced global reads; wave-per-position compute (lane = channel).
__global__ __launch_bounds__(256) void prep_kernel(
    const float* __restrict__ spt, const float* __restrict__ qry,
    const float* __restrict__ conv_w,
    const float* __restrict__ bng, const float* __restrict__ bnb,
    const float* __restrict__ bnm, const float* __restrict__ bnv,
    f16* __restrict__ sA, f16* __restrict__ qA,
    float* __restrict__ snT, float* __restrict__ qnT)
{
  __shared__ float xt[40 * 65];
  __shared__ float wl[64 * 65];
  const int tid = threadIdx.x;
  const int n = blockIdx.x / 10, p0 = (blockIdx.x - n * 10) * 40;
  const float* src = (n < WAY) ? (spt + n * PS) : (qry + (n - WAY) * PS);
  for (int i = tid; i < 4096; i += 256) wl[(i >> 6) * 65 + (i & 63)] = conv_w[i];
  for (int i = tid; i < 2560; i += 256) {
    const int c = i / 40, pp = i - c * 40;
    xt[pp * 65 + c] = src[c * 400 + p0 + pp];          // coalesced 40-float runs
  }
  __syncthreads();
  const int lane = tid & 63, wv = tid >> 6;
  const float bs = bng[lane] * rsqrtf(bnv[lane] + 1e-5f);
  const float bm = bnm[lane], bb = bnb[lane];
  f16* dA; float* dN;
  if (n < WAY) { dA = sA + n * PS; dN = snT + n * PS; }
  else { const int m = n - WAY; dA = qA + m * PS; dN = qnT + m * PS; }
  for (int i = 0; i < 10; ++i) {
    const int p = wv * 10 + i;
    const float x = xt[p * 65 + lane];
    const float mu = wave_sum(x) * (1.0f / 64.0f);
    const float xm = x - mu;
    dN[(p0 + p) * 64 + lane] = xm;                     // [pos][c] f32 for pooling
    float y = 0.f;
#pragma unroll
    for (int c = 0; c < 64; ++c)
      y = fmaf(wl[lane * 65 + c], __shfl(xm, c), y);
    y = fmaf(y - bm, bs, bb);
    y = fmaxf(y, 0.f);
    const float n2 = wave_sum(y * y);
    const float rn = 1.0f / fmaxf(sqrtf(n2), 1e-8f);
    dA[(p0 + p) * 64 + lane] = (f16)(y * rn);          // fp16 RNE, values in [0, ~0.6]
  }
}

// ---------------- corr: X[a,b] = F1[a].F2[b]; per-b gaussnorm+softmax over a (400);
//                  attn[a] = sum_b w[a,b]. Both modes in one launch. ----------------
// Block = (mode,pair), 8 waves, 64KB LDS -> 2 blocks/CU. F1 staged fp16 XOR-swizzled.
// Swapped MFMA: mfma(A=F2set, B=F1tile) -> lane l15 = a-index, (g,r) = b-column.
__global__ __launch_bounds__(512, 4) void corr_kernel(
    const f16* __restrict__ sA, const f16* __restrict__ qA,
    float* __restrict__ attn_s, float* __restrict__ attn_q)
{
  __shared__ f16 f1[25600];           // 51.2 KB, XOR-swizzled rows of 128B
  __shared__ float attn_sm[8 * 400];  // 12.8 KB
  const int bid = blockIdx.x;
  const int mode = (bid >= NPAIR) ? 1 : 0;
  const int pair = mode ? (bid - NPAIR) : bid;
  const int q = pair / WAY, w = pair - q * WAY;
  const f16 *F1, *F2; float* out;
  if (!mode) { F1 = sA + w * PS; F2 = qA + q * PS; out = attn_s + pair * P; }
  else       { F1 = qA + q * PS; F2 = sA + w * PS; out = attn_q + pair * P; }

  const int tid = threadIdx.x, lane = tid & 63, wv = tid >> 6;
  const int l15 = lane & 15, g = (lane >> 4) & 3;

  // stage F1 into LDS, XOR-swizzled (rows of 128B; byte ^= (row&7)<<4)
  for (int i = tid; i < 3200; i += 512) {
    const unsigned sw = ((unsigned)(i * 16)) ^ ((((unsigned)i >> 3) & 7u) << 4);
    *(f16x8*)((char*)f1 + sw) = *(const f16x8*)(F1 + i * 8);
  }
  for (int i = lane; i < P; i += 64) attn_sm[wv * P + i] = 0.f;
  __syncthreads();

  const unsigned sx = ((unsigned)(l15 & 7)) << 4;
  const unsigned b0 = ((unsigned)(l15 * 128 + g * 16)) ^ sx;
  const unsigned b1 = ((unsigned)(l15 * 128 + g * 16 + 64)) ^ sx;
  const char* f1B = (const char*)f1;

  for (int s = 0; s < 4; ++s) {
    const int tile = wv + 8 * s;
    if (tile >= 25) continue;                       // wave-uniform
    // A-operand: this set's 16 b-columns (from global, once per set)
    const int aoffB = (tile * 16 + l15) * 64 + g * 8;
    const f16x8 Ah0 = *(const f16x8*)(F2 + aoffB);
    const f16x8 Ah1 = *(const f16x8*)(F2 + aoffB + 32);

    f32x4 acc[25];
#pragma unroll
    for (int at = 0; at < 25; ++at) {
      const f16x8 Bh0 = *(const f16x8*)(f1B + at * 2048 + b0);
      const f16x8 Bh1 = *(const f16x8*)(f1B + at * 2048 + b1);
      f32x4 c = {0.f, 0.f, 0.f, 0.f};
      c = __builtin_amdgcn_mfma_f32_16x16x32_f16(Ah0, Bh0, c, 0, 0, 0);
      c = __builtin_amdgcn_mfma_f32_16x16x32_f16(Ah1, Bh1, c, 0, 0, 0);
      acc[at] = c;
    }
    // per-column (b) stats over 400 a-values: per-lane over at, then shfl over l15
    float sum0 = 0.f, sum1 = 0.f, sum2 = 0.f, sum3 = 0.f;
    float ssq0 = 0.f, ssq1 = 0.f, ssq2 = 0.f, ssq3 = 0.f;
#pragma unroll
    for (int at = 0; at < 25; ++at) {
      sum0 += acc[at][0]; ssq0 = fmaf(acc[at][0], acc[at][0], ssq0);
      sum1 += acc[at][1]; ssq1 = fmaf(acc[at][1], acc[at][1], ssq1);
      sum2 += acc[at][2]; ssq2 = fmaf(acc[at][2], acc[at][2], ssq2);
      sum3 += acc[at][3]; ssq3 = fmaf(acc[at][3], acc[at][3], ssq3);
    }
    float alpha[4], beta[4];
    float sums[4] = {sum0, sum1, sum2, sum3};
    float ssqs[4] = {ssq0, ssq1, ssq2, ssq3};
#pragma unroll
    for (int r = 0; r < 4; ++r) {
      float s_ = sums[r], q_ = ssqs[r];
      s_ += __shfl_xor(s_, 1); s_ += __shfl_xor(s_, 2); s_ += __shfl_xor(s_, 4); s_ += __shfl_xor(s_, 8);
      q_ += __shfl_xor(q_, 1); q_ += __shfl_xor(q_, 2); q_ += __shfl_xor(q_, 4); q_ += __shfl_xor(q_, 8);
      const float m_ = s_ * (1.0f / 400.0f);
      float var = fmaf(-400.0f * m_, m_, q_) * (1.0f / 399.0f);  // ddof=1
      var = fmaxf(var, 0.f);
      const float a_ = rsqrtf(var + 1e-5f) * TEMP_INV;           // rstd/TEMP
      alpha[r] = a_;
      beta[r] = -m_ * a_;                                        // fold mean into fma
    }
    // exp (no max-shift needed: |z|/T <= sqrt(399)/5 ~= 4) + column sums
    float se0 = 0.f, se1 = 0.f, se2 = 0.f, se3 = 0.f;
#pragma unroll
    for (int at = 0; at < 25; ++at) {
      const float e0 = __expf(fmaf(acc[at][0], alpha[0], beta[0]));
      const float e1 = __expf(fmaf(acc[at][1], alpha[1], beta[1]));
      const float e2 = __expf(fmaf(acc[at][2], alpha[2], beta[2]));
      const float e3 = __expf(fmaf(acc[at][3], alpha[3], beta[3]));
      acc[at][0] = e0; acc[at][1] = e1; acc[at][2] = e2; acc[at][3] = e3;
      se0 += e0; se1 += e1; se2 += e2; se3 += e3;
    }
    float inv[4];
    float ses[4] = {se0, se1, se2, se3};
#pragma unroll
    for (int r = 0; r < 4; ++r) {
      float s_ = ses[r];
      s_ += __shfl_xor(s_, 1); s_ += __shfl_xor(s_, 2); s_ += __shfl_xor(s_, 4); s_ += __shfl_xor(s_, 8);
      inv[r] = 1.0f / s_;
    }
    // attn[a] += sum over this set's 16 b-columns of e*inv
#pragma unroll
    for (int at = 0; at < 25; ++at) {
      float t = acc[at][0] * inv[0];
      t = fmaf(acc[at][1], inv[1], t);
      t = fmaf(acc[at][2], inv[2], t);
      t = fmaf(acc[at][3], inv[3], t);
      t += __shfl_xor(t, 16); t += __shfl_xor(t, 32);
      if (lane < 16) attn_sm[wv * P + at * 16 + lane] += t;
    }
  }
  __syncthreads();
  for (int a = tid; a < P; a += 512) {
    float s_ = 0.f;
#pragma unroll
    for (int k = 0; k < 8; ++k) s_ += attn_sm[k * P + a];
    out[a] = s_;
  }
}

// ---------------- pool: attention-weighted mean pooling + cosine ----------------
__global__ __launch_bounds__(256) void pool_kernel(
    const float* __restrict__ snT, const float* __restrict__ qnT,
    const float* __restrict__ attn_s, const float* __restrict__ attn_q,
    const float* __restrict__ scale, float* __restrict__ out)
{
  const int pair = blockIdx.x;
  const int q = pair / WAY, w = pair - q * WAY;
  const int tid = threadIdx.x, lane = tid & 63, wv = tid >> 6;
  const float* sn = snT + w * PS;
  const float* qn = qnT + q * PS;
  const float* as_ = attn_s + pair * P;
  const float* aq_ = attn_q + pair * P;
  float accs = 0.f, accq = 0.f;
  for (int p = wv; p < P; p += 4) {
    accs = fmaf(as_[p], sn[p * 64 + lane], accs);
    accq = fmaf(aq_[p], qn[p * 64 + lane], accq);
  }
  __shared__ float buf[2][4][64];
  buf[0][wv][lane] = accs;
  buf[1][wv][lane] = accq;
  __syncthreads();
  if (wv == 0) {
    const float sa = (buf[0][0][lane] + buf[0][1][lane] + buf[0][2][lane] + buf[0][3][lane]) * (1.0f / 400.0f);
    const float qa = (buf[1][0][lane] + buf[1][1][lane] + buf[1][2][lane] + buf[1][3][lane]) * (1.0f / 400.0f);
    const float d   = wave_sum(sa * qa);
    const float ns  = wave_sum(sa * sa);
    const float nq2 = wave_sum(qa * qa);
    if (lane == 0) {
      const float den = fmaxf(sqrtf(ns), 1e-6f) * fmaxf(sqrtf(nq2), 1e-6f);
      out[pair] = d / den * scale[0];
    }
  }
}

extern "C" void kernel_launch(void* const* d_in, const int* in_sizes, int n_in,
                              void* d_out, int out_size, void* d_ws, size_t ws_size,
                              hipStream_t stream) {
  const float* spt    = (const float*)d_in[0];
  const float* qry    = (const float*)d_in[1];
  const float* conv_w = (const float*)d_in[2];
  const float* bng    = (const float*)d_in[3];
  const float* bnb    = (const float*)d_in[4];
  const float* bnm    = (const float*)d_in[5];
  const float* bnv    = (const float*)d_in[6];
  const float* scale  = (const float*)d_in[7];
  float* out = (float*)d_out;

  char* p = (char*)d_ws;
  f16* sA = (f16*)p;     p += (size_t)WAY * PS * 2;
  f16* qA = (f16*)p;     p += (size_t)NQ * PS * 2;
  float* snT = (float*)p;    p += (size_t)WAY * PS * 4;
  float* qnT = (float*)p;    p += (size_t)NQ * PS * 4;
  float* attn_s = (float*)p; p += (size_t)NPAIR * P * 4;
  float* attn_q = (float*)p;

  prep_kernel<<<dim3(800), dim3(256), 0, stream>>>(
      spt, qry, conv_w, bng, bnb, bnm, bnv, sA, qA, snT, qnT);
  corr_kernel<<<dim3(2 * NPAIR), dim3(512), 0, stream>>>(
      sA, qA, attn_s, attn_q);
  pool_kernel<<<dim3(NPAIR), dim3(256), 0, stream>>>(
      snT, qnT, attn_s, attn_q, scale, out);
}

// Round 5
// 135.597 us; speedup vs baseline: 5.1232x; 1.1073x over previous
//
#include <hip/hip_runtime.h>

#define WAY 5
#define NQ 75
#define P 400              // 20*20 positions
#define PS (P*64)          // 25600 elements per sample
#define NPAIR (NQ*WAY)     // 375
#define TEMP_INV 0.2f      // 1/5.0

typedef unsigned short u16;
typedef _Float16 f16;
typedef __attribute__((ext_vector_type(8))) _Float16 f16x8;
typedef __attribute__((ext_vector_type(2))) __fp16 h16x2;   // cvt_pkrtz return type
typedef __attribute__((ext_vector_type(4))) float f32x4;

__device__ __forceinline__ float wave_sum(float v) {
  v += __shfl_xor(v, 1);  v += __shfl_xor(v, 2);  v += __shfl_xor(v, 4);
  v += __shfl_xor(v, 8);  v += __shfl_xor(v, 16); v += __shfl_xor(v, 32);
  return v;
}

// ---------------- prep: normalize_feature -> conv1x1 -> BN -> ReLU -> L2norm ----------------
// 800 blocks = 80 samples x 10 chunks of 40 positions. LDS-transposed staging for
// coalesced global reads; wave-per-position compute (lane = channel).
__global__ __launch_bounds__(256) void prep_kernel(
    const float* __restrict__ spt, const float* __restrict__ qry,
    const float* __restrict__ conv_w,
    const float* __restrict__ bng, const float* __restrict__ bnb,
    const float* __restrict__ bnm, const float* __restrict__ bnv,
    f16* __restrict__ sA, f16* __restrict__ qA,
    float* __restrict__ snT, float* __restrict__ qnT)
{
  __shared__ float xt[40 * 65];
  __shared__ float wl[64 * 65];
  const int tid = threadIdx.x;
  const int n = blockIdx.x / 10, p0 = (blockIdx.x - n * 10) * 40;
  const float* src = (n < WAY) ? (spt + n * PS) : (qry + (n - WAY) * PS);
  for (int i = tid; i < 4096; i += 256) wl[(i >> 6) * 65 + (i & 63)] = conv_w[i];
  for (int i = tid; i < 2560; i += 256) {
    const int c = i / 40, pp = i - c * 40;
    xt[pp * 65 + c] = src[c * 400 + p0 + pp];          // coalesced 40-float runs
  }
  __syncthreads();
  const int lane = tid & 63, wv = tid >> 6;
  const float bs = bng[lane] * rsqrtf(bnv[lane] + 1e-5f);
  const float bm = bnm[lane], bb = bnb[lane];
  f16* dA; float* dN;
  if (n < WAY) { dA = sA + n * PS; dN = snT + n * PS; }
  else { const int m = n - WAY; dA = qA + m * PS; dN = qnT + m * PS; }
  for (int i = 0; i < 10; ++i) {
    const int p = wv * 10 + i;
    const float x = xt[p * 65 + lane];
    const float mu = wave_sum(x) * (1.0f / 64.0f);
    const float xm = x - mu;
    dN[(p0 + p) * 64 + lane] = xm;                     // [pos][c] f32 for pooling
    float y = 0.f;
#pragma unroll
    for (int c = 0; c < 64; ++c)
      y = fmaf(wl[lane * 65 + c], __shfl(xm, c), y);
    y = fmaf(y - bm, bs, bb);
    y = fmaxf(y, 0.f);
    const float n2 = wave_sum(y * y);
    const float rn = 1.0f / fmaxf(sqrtf(n2), 1e-8f);
    dA[(p0 + p) * 64 + lane] = (f16)(y * rn);          // fp16 RNE, values in [0, ~0.6]
  }
}

// ---------------- corr: X[a,b] = F1[a].F2[b]; per-b gaussnorm+softmax over a (400);
//                  attn[a] = sum_b w[a,b]. Both modes in one launch. ----------------
// Block = (mode,pair), 8 waves, 64KB LDS -> 2 blocks/CU. F1 staged fp16 XOR-swizzled.
// Swapped MFMA: mfma(A=F2set, B=F1tile) -> lane l15 = a-index, (g,r) = b-column.
// Per-lane X state packed to f16 pairs (50 VGPRs) so everything fits under the
// 128-reg cap for 4 waves/SIMD; stats computed on f32 values inline (no loss).
__global__ __launch_bounds__(512, 4) void corr_kernel(
    const f16* __restrict__ sA, const f16* __restrict__ qA,
    float* __restrict__ attn_s, float* __restrict__ attn_q)
{
  __shared__ f16 f1[25600];           // 51.2 KB, XOR-swizzled rows of 128B
  __shared__ float attn_sm[8 * 400];  // 12.8 KB
  const int bid = blockIdx.x;
  const int mode = (bid >= NPAIR) ? 1 : 0;
  const int pair = mode ? (bid - NPAIR) : bid;
  const int q = pair / WAY, w = pair - q * WAY;
  const f16 *F1, *F2; float* out;
  if (!mode) { F1 = sA + w * PS; F2 = qA + q * PS; out = attn_s + pair * P; }
  else       { F1 = qA + q * PS; F2 = sA + w * PS; out = attn_q + pair * P; }

  const int tid = threadIdx.x, lane = tid & 63, wv = tid >> 6;
  const int l15 = lane & 15, g = (lane >> 4) & 3;

  // stage F1 into LDS, XOR-swizzled (rows of 128B; byte ^= (row&7)<<4)
  for (int i = tid; i < 3200; i += 512) {
    const unsigned sw = ((unsigned)(i * 16)) ^ ((((unsigned)i >> 3) & 7u) << 4);
    *(f16x8*)((char*)f1 + sw) = *(const f16x8*)(F1 + i * 8);
  }
  for (int i = lane; i < P; i += 64) attn_sm[wv * P + i] = 0.f;
  __syncthreads();

  const unsigned sx = ((unsigned)(l15 & 7)) << 4;
  const unsigned b0 = ((unsigned)(l15 * 128 + g * 16)) ^ sx;
  const unsigned b1 = ((unsigned)(l15 * 128 + g * 16 + 64)) ^ sx;
  const char* f1B = (const char*)f1;

  for (int s = 0; s < 4; ++s) {
    const int tile = wv + 8 * s;
    if (tile >= 25) continue;                       // wave-uniform
    // A-operand: this set's 16 b-columns (from global, once per set)
    const int aoffB = (tile * 16 + l15) * 64 + g * 8;
    const f16x8 Ah0 = *(const f16x8*)(F2 + aoffB);
    const f16x8 Ah1 = *(const f16x8*)(F2 + aoffB + 32);

    h16x2 packed[50];                               // X (later e), f16-packed
    float sum0 = 0.f, sum1 = 0.f, sum2 = 0.f, sum3 = 0.f;
    float ssq0 = 0.f, ssq1 = 0.f, ssq2 = 0.f, ssq3 = 0.f;
#pragma unroll
    for (int at = 0; at < 25; ++at) {
      const f16x8 Bh0 = *(const f16x8*)(f1B + at * 2048 + b0);
      const f16x8 Bh1 = *(const f16x8*)(f1B + at * 2048 + b1);
      f32x4 c = {0.f, 0.f, 0.f, 0.f};
      c = __builtin_amdgcn_mfma_f32_16x16x32_f16(Ah0, Bh0, c, 0, 0, 0);
      c = __builtin_amdgcn_mfma_f32_16x16x32_f16(Ah1, Bh1, c, 0, 0, 0);
      sum0 += c[0]; ssq0 = fmaf(c[0], c[0], ssq0);
      sum1 += c[1]; ssq1 = fmaf(c[1], c[1], ssq1);
      sum2 += c[2]; ssq2 = fmaf(c[2], c[2], ssq2);
      sum3 += c[3]; ssq3 = fmaf(c[3], c[3], ssq3);
      packed[2 * at]     = __builtin_amdgcn_cvt_pkrtz(c[0], c[1]);
      packed[2 * at + 1] = __builtin_amdgcn_cvt_pkrtz(c[2], c[3]);
    }
    // per-column (b) stats over the 400 a-values: shfl over l15 group
    float alpha[4], beta[4];
    {
      float sums[4] = {sum0, sum1, sum2, sum3};
      float ssqs[4] = {ssq0, ssq1, ssq2, ssq3};
#pragma unroll
      for (int r = 0; r < 4; ++r) {
        float s_ = sums[r], q_ = ssqs[r];
        s_ += __shfl_xor(s_, 1); s_ += __shfl_xor(s_, 2); s_ += __shfl_xor(s_, 4); s_ += __shfl_xor(s_, 8);
        q_ += __shfl_xor(q_, 1); q_ += __shfl_xor(q_, 2); q_ += __shfl_xor(q_, 4); q_ += __shfl_xor(q_, 8);
        const float m_ = s_ * (1.0f / 400.0f);
        float var = fmaf(-400.0f * m_, m_, q_) * (1.0f / 399.0f);  // ddof=1
        var = fmaxf(var, 0.f);
        const float a_ = rsqrtf(var + 1e-5f) * TEMP_INV;           // rstd/TEMP
        alpha[r] = a_;
        beta[r] = -m_ * a_;                                        // fold mean into fma
      }
    }
    // exp (no max-shift needed: |z|/T <= sqrt(399)/5 ~= 4) + column sums
    float se0 = 0.f, se1 = 0.f, se2 = 0.f, se3 = 0.f;
#pragma unroll
    for (int at = 0; at < 25; ++at) {
      const h16x2 p0 = packed[2 * at], p1 = packed[2 * at + 1];
      const float e0 = __expf(fmaf((float)p0[0], alpha[0], beta[0]));
      const float e1 = __expf(fmaf((float)p0[1], alpha[1], beta[1]));
      const float e2 = __expf(fmaf((float)p1[0], alpha[2], beta[2]));
      const float e3 = __expf(fmaf((float)p1[1], alpha[3], beta[3]));
      se0 += e0; se1 += e1; se2 += e2; se3 += e3;
      packed[2 * at]     = __builtin_amdgcn_cvt_pkrtz(e0, e1);
      packed[2 * at + 1] = __builtin_amdgcn_cvt_pkrtz(e2, e3);
    }
    float inv[4];
    {
      float ses[4] = {se0, se1, se2, se3};
#pragma unroll
      for (int r = 0; r < 4; ++r) {
        float s_ = ses[r];
        s_ += __shfl_xor(s_, 1); s_ += __shfl_xor(s_, 2); s_ += __shfl_xor(s_, 4); s_ += __shfl_xor(s_, 8);
        inv[r] = 1.0f / s_;
      }
    }
    // attn[a] += sum over this set's 16 b-columns of e*inv
#pragma unroll
    for (int at = 0; at < 25; ++at) {
      const h16x2 p0 = packed[2 * at], p1 = packed[2 * at + 1];
      float t = (float)p0[0] * inv[0];
      t = fmaf((float)p0[1], inv[1], t);
      t = fmaf((float)p1[0], inv[2], t);
      t = fmaf((float)p1[1], inv[3], t);
      t += __shfl_xor(t, 16); t += __shfl_xor(t, 32);
      if (lane < 16) attn_sm[wv * P + at * 16 + lane] += t;
    }
  }
  __syncthreads();
  for (int a = tid; a < P; a += 512) {
    float s_ = 0.f;
#pragma unroll
    for (int k = 0; k < 8; ++k) s_ += attn_sm[k * P + a];
    out[a] = s_;
  }
}

// ---------------- pool: attention-weighted mean pooling + cosine ----------------
__global__ __launch_bounds__(256) void pool_kernel(
    const float* __restrict__ snT, const float* __restrict__ qnT,
    const float* __restrict__ attn_s, const float* __restrict__ attn_q,
    const float* __restrict__ scale, float* __restrict__ out)
{
  const int pair = blockIdx.x;
  const int q = pair / WAY, w = pair - q * WAY;
  const int tid = threadIdx.x, lane = tid & 63, wv = tid >> 6;
  const float* sn = snT + w * PS;
  const float* qn = qnT + q * PS;
  const float* as_ = attn_s + pair * P;
  const float* aq_ = attn_q + pair * P;
  float accs = 0.f, accq = 0.f;
  for (int p = wv; p < P; p += 4) {
    accs = fmaf(as_[p], sn[p * 64 + lane], accs);
    accq = fmaf(aq_[p], qn[p * 64 + lane], accq);
  }
  __shared__ float buf[2][4][64];
  buf[0][wv][lane] = accs;
  buf[1][wv][lane] = accq;
  __syncthreads();
  if (wv == 0) {
    const float sa = (buf[0][0][lane] + buf[0][1][lane] + buf[0][2][lane] + buf[0][3][lane]) * (1.0f / 400.0f);
    const float qa = (buf[1][0][lane] + buf[1][1][lane] + buf[1][2][lane] + buf[1][3][lane]) * (1.0f / 400.0f);
    const float d   = wave_sum(sa * qa);
    const float ns  = wave_sum(sa * sa);
    const float nq2 = wave_sum(qa * qa);
    if (lane == 0) {
      const float den = fmaxf(sqrtf(ns), 1e-6f) * fmaxf(sqrtf(nq2), 1e-6f);
      out[pair] = d / den * scale[0];
    }
  }
}

extern "C" void kernel_launch(void* const* d_in, const int* in_sizes, int n_in,
                              void* d_out, int out_size, void* d_ws, size_t ws_size,
                              hipStream_t stream) {
  const float* spt    = (const float*)d_in[0];
  const float* qry    = (const float*)d_in[1];
  const float* conv_w = (const float*)d_in[2];
  const float* bng    = (const float*)d_in[3];
  const float* bnb    = (const float*)d_in[4];
  const float* bnm    = (const float*)d_in[5];
  const float* bnv    = (const float*)d_in[6];
  const float* scale  = (const float*)d_in[7];
  float* out = (float*)d_out;

  char* p = (char*)d_ws;
  f16* sA = (f16*)p;     p += (size_t)WAY * PS * 2;
  f16* qA = (f16*)p;     p += (size_t)NQ * PS * 2;
  float* snT = (float*)p;    p += (size_t)WAY * PS * 4;
  float* qnT = (float*)p;    p += (size_t)NQ * PS * 4;
  float* attn_s = (float*)p; p += (size_t)NPAIR * P * 4;
  float* attn_q = (float*)p;

  prep_kernel<<<dim3(800), dim3(256), 0, stream>>>(
      spt, qry, conv_w, bng, bnb, bnm, bnv, sA, qA, snT, qnT);
  corr_kernel<<<dim3(2 * NPAIR), dim3(512), 0, stream>>>(
      sA, qA, attn_s, attn_q);
  pool_kernel<<<dim3(NPAIR), dim3(256), 0, stream>>>(
      snT, qnT, attn_s, attn_q, scale, out);
}